// Round 5
// baseline (344.441 us; speedup 1.0000x reference)
//
#include <hip/hip_runtime.h>
#include <math.h>

// Problem constants: B=8, S=4096, D=1024, Q=16  -> 32768 rows
#define ROWS_TOTAL 32768
#define DDIM 1024
#define QDIM 16

// ===========================================================================
// Pass 1: z[r][q] = cos(relu(x[r]·W1[:,q] + b1[q]) + theta[q])
//
// Lane layout (64 = 4 k-interleave x 4 rows x 4 q-quads):
//   qg = lane&3        q = 4qg..4qg+3
//   rr = (lane>>2)&3   row = wv*4+rr
//   kq = lane>>4       INTERLEAVED k: stage s covers k in [16s,16s+16);
//                      lane kq takes k = 16s+4kq .. +3
// Interleave (vs R4's private 1KB k-quarters) makes the 4 kq lanes of a row
// read CONTIGUOUS 64B per x instruction: 4 line-requests/instr instead of
// 16. R4 was latency-bound (VALUBusy 8.9%, HBM 7.5%, occ 33%) with queue
// pressure from 16-line divergent loads. 4 rows/wave -> 2048 blocks -> up
// to 8 waves/SIMD at ~40 VGPR (R4's depth-2 schedule needed 44).
// Dot-product order change is just fp reassociation (already reassociated).
// ===========================================================================
#define K1_TPB 256
#define K1_NBLOCKS (ROWS_TOTAL / 4 / (K1_TPB / 64))  // 2048

__global__ __launch_bounds__(K1_TPB)
void qz_kernel(const float* __restrict__ x, const float* __restrict__ W1,
               const float* __restrict__ b1, const float* __restrict__ theta,
               float* __restrict__ z) {
  const int lane = threadIdx.x & 63;
  const int wv = blockIdx.x * (K1_TPB / 64) + (threadIdx.x >> 6);
  const int qg = lane & 3;
  const int rr = (lane >> 2) & 3;
  const int kq = lane >> 4;
  const int row = wv * 4 + rr;

  // stage s: x float4 at xp + 16s; W1 rows 16s+4kq+j (j=0..3), cols 4qg..
  const float* xp = x + (size_t)row * DDIM + 4 * kq;
  const float* wp = W1 + (size_t)(4 * kq) * QDIM + 4 * qg;

  float4 acc = make_float4(0.f, 0.f, 0.f, 0.f);

  // acc.c += xv.j * wj.c  (j = k-offset, c = q-offset) — 16 FMA per call.
  auto fma16 = [](float4& a, const float4 xv, const float4 w0, const float4 w1,
                  const float4 w2, const float4 w3) {
    a.x = fmaf(xv.x, w0.x, a.x); a.y = fmaf(xv.x, w0.y, a.y);
    a.z = fmaf(xv.x, w0.z, a.z); a.w = fmaf(xv.x, w0.w, a.w);
    a.x = fmaf(xv.y, w1.x, a.x); a.y = fmaf(xv.y, w1.y, a.y);
    a.z = fmaf(xv.y, w1.z, a.z); a.w = fmaf(xv.y, w1.w, a.w);
    a.x = fmaf(xv.z, w2.x, a.x); a.y = fmaf(xv.z, w2.y, a.y);
    a.z = fmaf(xv.z, w2.z, a.z); a.w = fmaf(xv.z, w2.w, a.w);
    a.x = fmaf(xv.w, w3.x, a.x); a.y = fmaf(xv.w, w3.y, a.y);
    a.z = fmaf(xv.w, w3.z, a.z); a.w = fmaf(xv.w, w3.w, a.w);
  };

  // prologue: x double-buffered (xa=even stage, xb=odd), W1 for stage 0
  float4 xa = *reinterpret_cast<const float4*>(xp + 16 * 0);
  float4 xb = *reinterpret_cast<const float4*>(xp + 16 * 1);
  float4 wa0 = *reinterpret_cast<const float4*>(wp + (size_t)(16 * 0 + 0) * QDIM);
  float4 wa1 = *reinterpret_cast<const float4*>(wp + (size_t)(16 * 0 + 1) * QDIM);
  float4 wa2 = *reinterpret_cast<const float4*>(wp + (size_t)(16 * 0 + 2) * QDIM);
  float4 wa3 = *reinterpret_cast<const float4*>(wp + (size_t)(16 * 0 + 3) * QDIM);

#pragma unroll 1
  for (int s = 0; s < 64; s += 2) {
    // W for odd stage s+1 (issued before even-stage FMAs)
    const float* pwb = wp + (size_t)(16 * (s + 1)) * QDIM;
    const float4 wb0 = *reinterpret_cast<const float4*>(pwb + 0 * QDIM);
    const float4 wb1 = *reinterpret_cast<const float4*>(pwb + 1 * QDIM);
    const float4 wb2 = *reinterpret_cast<const float4*>(pwb + 2 * QDIM);
    const float4 wb3 = *reinterpret_cast<const float4*>(pwb + 3 * QDIM);

    // even stage s
    fma16(acc, xa, wa0, wa1, wa2, wa3);

    // prefetch x for stage s+2 (clamped on last iter; redundant re-read ok)
    const int sp = (s + 2 < 64) ? (s + 2) : 0;
    xa = *reinterpret_cast<const float4*>(xp + 16 * sp);

    // W for even stage s+2
    const float* pwa = wp + (size_t)(16 * sp) * QDIM;
    wa0 = *reinterpret_cast<const float4*>(pwa + 0 * QDIM);
    wa1 = *reinterpret_cast<const float4*>(pwa + 1 * QDIM);
    wa2 = *reinterpret_cast<const float4*>(pwa + 2 * QDIM);
    wa3 = *reinterpret_cast<const float4*>(pwa + 3 * QDIM);

    // odd stage s+1
    fma16(acc, xb, wb0, wb1, wb2, wb3);

    // prefetch x for stage s+3
    const int sq = (s + 3 < 64) ? (s + 3) : 1;
    xb = *reinterpret_cast<const float4*>(xp + 16 * sq);
  }

  // merge the 4 k-interleave groups: butterfly over lane bits 4 and 5
  auto red = [](float v) {
    v += __shfl_xor(v, 16);
    v += __shfl_xor(v, 32);
    return v;
  };
  acc.x = red(acc.x); acc.y = red(acc.y);
  acc.z = red(acc.z); acc.w = red(acc.w);

  // lanes 0..15 (kq==0) hold full sums: 4 rows x 4 q-quads -> 256B store
  if (kq == 0) {
    const float4 b1v = *reinterpret_cast<const float4*>(b1 + 4 * qg);
    const float4 thv = *reinterpret_cast<const float4*>(theta + 4 * qg);
    float4 zv;
    zv.x = __cosf(fmaxf(acc.x + b1v.x, 0.f) + thv.x);
    zv.y = __cosf(fmaxf(acc.y + b1v.y, 0.f) + thv.y);
    zv.z = __cosf(fmaxf(acc.z + b1v.z, 0.f) + thv.z);
    zv.w = __cosf(fmaxf(acc.w + b1v.w, 0.f) + thv.w);
    *reinterpret_cast<float4*>(z + (size_t)row * QDIM + 4 * qg) = zv;
  }
}

// ===========================================================================
// Pass 2: out[r][d] = b2[d] + sum_q z[r][q] * W2[q][d]
// 512 threads, 2 cols/thread: W2 slice in 16 NAMED float2 (32 VGPR) so the
// whole kernel fits ~58 VGPR -> 8 waves/SIMD, 32 waves/CU (the 4-col
// variant needs ~90 VGPR -> 4 waves/SIMD). Per row: 4 broadcast float4
// z-loads (L2-hot, 1 line/instr) + 32 FMA + one coalesced float2 store
// (512x8B = 4KB/instr-pair). Zero LDS, zero barriers; TLP hides z latency.
// ===========================================================================
#define K2_TPB 512
#define K2_ROWS 32
#define K2_NBLOCKS (ROWS_TOTAL / K2_ROWS)  // 1024

__global__ __launch_bounds__(K2_TPB)
void out_kernel(const float* __restrict__ z, const float* __restrict__ W2,
                const float* __restrict__ b2, float* __restrict__ out) {
  const int t = threadIdx.x;
  const float* wb = W2 + 2 * t;

  const float2 w00 = *reinterpret_cast<const float2*>(wb + 0 * DDIM);
  const float2 w01 = *reinterpret_cast<const float2*>(wb + 1 * DDIM);
  const float2 w02 = *reinterpret_cast<const float2*>(wb + 2 * DDIM);
  const float2 w03 = *reinterpret_cast<const float2*>(wb + 3 * DDIM);
  const float2 w04 = *reinterpret_cast<const float2*>(wb + 4 * DDIM);
  const float2 w05 = *reinterpret_cast<const float2*>(wb + 5 * DDIM);
  const float2 w06 = *reinterpret_cast<const float2*>(wb + 6 * DDIM);
  const float2 w07 = *reinterpret_cast<const float2*>(wb + 7 * DDIM);
  const float2 w08 = *reinterpret_cast<const float2*>(wb + 8 * DDIM);
  const float2 w09 = *reinterpret_cast<const float2*>(wb + 9 * DDIM);
  const float2 w10 = *reinterpret_cast<const float2*>(wb + 10 * DDIM);
  const float2 w11 = *reinterpret_cast<const float2*>(wb + 11 * DDIM);
  const float2 w12 = *reinterpret_cast<const float2*>(wb + 12 * DDIM);
  const float2 w13 = *reinterpret_cast<const float2*>(wb + 13 * DDIM);
  const float2 w14 = *reinterpret_cast<const float2*>(wb + 14 * DDIM);
  const float2 w15 = *reinterpret_cast<const float2*>(wb + 15 * DDIM);
  const float2 b2v = *reinterpret_cast<const float2*>(b2 + 2 * t);

  // a += zq.{x,y,z,w} * wA..wD  (8 FMAs: one z-quad against 4 W2 rows)
  auto fmaq = [](float2& a, const float4 zq, const float2 wA, const float2 wB,
                 const float2 wC, const float2 wD) {
    a.x = fmaf(zq.x, wA.x, a.x); a.y = fmaf(zq.x, wA.y, a.y);
    a.x = fmaf(zq.y, wB.x, a.x); a.y = fmaf(zq.y, wB.y, a.y);
    a.x = fmaf(zq.z, wC.x, a.x); a.y = fmaf(zq.z, wC.y, a.y);
    a.x = fmaf(zq.w, wD.x, a.x); a.y = fmaf(zq.w, wD.y, a.y);
  };

  const int r0 = blockIdx.x * K2_ROWS;
  const float* zp = z + (size_t)r0 * QDIM;
  float* op = out + (size_t)r0 * DDIM + 2 * t;

#pragma unroll 4
  for (int i = 0; i < K2_ROWS; ++i) {
    const float4 z0 = *reinterpret_cast<const float4*>(zp + i * QDIM + 0);
    const float4 z1 = *reinterpret_cast<const float4*>(zp + i * QDIM + 4);
    const float4 z2 = *reinterpret_cast<const float4*>(zp + i * QDIM + 8);
    const float4 z3 = *reinterpret_cast<const float4*>(zp + i * QDIM + 12);
    float2 a = b2v;
    fmaq(a, z0, w00, w01, w02, w03);
    fmaq(a, z1, w04, w05, w06, w07);
    fmaq(a, z2, w08, w09, w10, w11);
    fmaq(a, z3, w12, w13, w14, w15);
    *reinterpret_cast<float2*>(op + (size_t)i * DDIM) = a;
  }
}

// ===========================================================================
// Fallback: previous best fused kernel (used only if ws_size < 2 MB).
// ===========================================================================
#define TPB 512
#define RPB 16
#define R 4
#define NPH (RPB / R)
#define NBLOCKS (ROWS_TOTAL / RPB)

__global__ __launch_bounds__(TPB, 4)
void ffq_kernel(const float* __restrict__ x, const float* __restrict__ W1,
                const float* __restrict__ b1, const float* __restrict__ theta,
                const float* __restrict__ W2, const float* __restrict__ b2,
                float* __restrict__ out) {
  const int t    = threadIdx.x;
  const int lane = t & 63;
  const int wid  = t >> 6;
  const int qg   = t & 3;
  const int c    = t >> 2;
  const int q5   = lane & 15;
  const int r5   = lane >> 4;

  __shared__ __align__(16) float hw[2][16][R][QDIM];
  __shared__ __align__(16) float zs[8][R][QDIM];

  float w1r[8][4];
  {
    const float* p = W1 + (size_t)(8 * c) * QDIM + 4 * qg;
#pragma unroll
    for (int j = 0; j < 8; ++j) {
      float4 v = *reinterpret_cast<const float4*>(p + (size_t)j * QDIM);
      w1r[j][0] = v.x; w1r[j][1] = v.y; w1r[j][2] = v.z; w1r[j][3] = v.w;
    }
  }
  float w2r[QDIM][2];
#pragma unroll
  for (int q = 0; q < QDIM; ++q) {
    float2 v = *reinterpret_cast<const float2*>(W2 + (size_t)q * DDIM + 2 * t);
    w2r[q][0] = v.x; w2r[q][1] = v.y;
  }
  const float2 b2r = *reinterpret_cast<const float2*>(b2 + 2 * t);
  const float b1q = b1[q5];
  const float thq = theta[q5];

  const int row0 = blockIdx.x * RPB;

  float4 xa[R], xb[R];
  {
    const float* p = x + (size_t)row0 * DDIM + 8 * c;
#pragma unroll
    for (int r = 0; r < R; ++r) {
      xa[r] = *reinterpret_cast<const float4*>(p + (size_t)r * DDIM);
      xb[r] = *reinterpret_cast<const float4*>(p + (size_t)r * DDIM + 4);
    }
  }

  auto mm2_store = [&](int rowp) {
#pragma unroll
    for (int r = 0; r < R; ++r) {
      float o0 = b2r.x, o1 = b2r.y;
#pragma unroll
      for (int jb = 0; jb < 4; ++jb) {
        float4 zv = *reinterpret_cast<const float4*>(&zs[wid][r][4 * jb]);
        o0 = fmaf(zv.x, w2r[4 * jb + 0][0], o0);
        o1 = fmaf(zv.x, w2r[4 * jb + 0][1], o1);
        o0 = fmaf(zv.y, w2r[4 * jb + 1][0], o0);
        o1 = fmaf(zv.y, w2r[4 * jb + 1][1], o1);
        o0 = fmaf(zv.z, w2r[4 * jb + 2][0], o0);
        o1 = fmaf(zv.z, w2r[4 * jb + 2][1], o1);
        o0 = fmaf(zv.w, w2r[4 * jb + 3][0], o0);
        o1 = fmaf(zv.w, w2r[4 * jb + 3][1], o1);
      }
      *reinterpret_cast<float2*>(out + (size_t)(rowp + r) * DDIM + 2 * t) =
          make_float2(o0, o1);
    }
  };

  for (int ph = 0; ph < NPH; ++ph) {
    const int buf = ph & 1;

    float hp[R][4];
#pragma unroll
    for (int r = 0; r < R; ++r) {
      const float xv[8] = {xa[r].x, xa[r].y, xa[r].z, xa[r].w,
                           xb[r].x, xb[r].y, xb[r].z, xb[r].w};
      float h0 = 0.f, h1 = 0.f, h2 = 0.f, h3 = 0.f;
#pragma unroll
      for (int j = 0; j < 8; ++j) {
        h0 = fmaf(xv[j], w1r[j][0], h0);
        h1 = fmaf(xv[j], w1r[j][1], h1);
        h2 = fmaf(xv[j], w1r[j][2], h2);
        h3 = fmaf(xv[j], w1r[j][3], h3);
      }
      hp[r][0] = h0; hp[r][1] = h1; hp[r][2] = h2; hp[r][3] = h3;
    }

#pragma unroll
    for (int m = 4; m <= 16; m <<= 1)
#pragma unroll
      for (int r = 0; r < R; ++r)
#pragma unroll
        for (int qq = 0; qq < 4; ++qq)
          hp[r][qq] += __shfl_xor(hp[r][qq], m, 64);

    if ((lane & 28) == 0) {
      const int j = wid * 2 + (lane >> 5);
#pragma unroll
      for (int r = 0; r < R; ++r)
        *reinterpret_cast<float4*>(&hw[buf][j][r][4 * qg]) =
            make_float4(hp[r][0], hp[r][1], hp[r][2], hp[r][3]);
    }
    __syncthreads();

    if (ph + 1 < NPH) {
      const float* p = x + (size_t)(row0 + (ph + 1) * R) * DDIM + 8 * c;
#pragma unroll
      for (int r = 0; r < R; ++r) {
        xa[r] = *reinterpret_cast<const float4*>(p + (size_t)r * DDIM);
        xb[r] = *reinterpret_cast<const float4*>(p + (size_t)r * DDIM + 4);
      }
    }

    if (ph > 0) mm2_store(row0 + (ph - 1) * R);

    float s = 0.f;
#pragma unroll
    for (int j = 0; j < 16; ++j) s += hw[buf][j][r5][q5];
    s = fmaxf(s + b1q, 0.f) + thq;
    zs[wid][r5][q5] = __cosf(s);
  }

  __syncthreads();
  mm2_store(row0 + (NPH - 1) * R);
}

extern "C" void kernel_launch(void* const* d_in, const int* in_sizes, int n_in,
                              void* d_out, int out_size, void* d_ws, size_t ws_size,
                              hipStream_t stream) {
  const float* x     = (const float*)d_in[0];
  const float* W1    = (const float*)d_in[1];
  const float* b1    = (const float*)d_in[2];
  const float* theta = (const float*)d_in[3];
  const float* W2    = (const float*)d_in[4];
  const float* b2    = (const float*)d_in[5];
  float* out = (float*)d_out;

  const size_t z_bytes = (size_t)ROWS_TOTAL * QDIM * sizeof(float);  // 2 MiB
  if (ws_size >= z_bytes && d_ws != nullptr) {
    float* z = (float*)d_ws;
    qz_kernel<<<dim3(K1_NBLOCKS), dim3(K1_TPB), 0, stream>>>(x, W1, b1, theta, z);
    out_kernel<<<dim3(K2_NBLOCKS), dim3(K2_TPB), 0, stream>>>(z, W2, b2, out);
  } else {
    ffq_kernel<<<dim3(NBLOCKS), dim3(TPB), 0, stream>>>(x, W1, b1, theta, W2, b2, out);
  }
}

// Round 7
// 262.394 us; speedup vs baseline: 1.3127x; 1.3127x over previous
//
#include <hip/hip_runtime.h>
#include <math.h>

// Problem constants: B=8, S=4096, D=1024, Q=16  -> 32768 rows
#define ROWS_TOTAL 32768
#define DDIM 1024
#define QDIM 16

typedef float f32x4 __attribute__((ext_vector_type(4)));  // for nt-store

// ===========================================================================
// Pass 1: z[r][q] = cos(relu(x[r]·W1[:,q] + b1[q]) + theta[q])
//
// R4/R5 post-mortem: per-lane serial-K designs are VMEM-INSTRUCTION bound
// (TA pipe ~16 cyc/wave-instr): R5 issued ~10 mem-instrs per 32 FMA-instrs
// and sat at VALUBusy 7%. This version maximizes FLOP per memory
// instruction:
//   - wave owns 8 rows; K walked in 16 steps of 64
//   - x staged to per-wave LDS tile via 2 global_load_lds (width 16) per
//     step: 1KB unique/instr, x read exactly once, no VGPR round-trip,
//     double-buffered, counted vmcnt(6) (never 0 mid-loop), NO barriers
//   - W1: 4 coalesced float4 loads/step into named regs, double-buffered
//   - per step: 14 mem-instrs feed 128 FMA-instrs
//   - epilogue: 3-stage shuffle reduce-scatter (+1 butterfly) = 32 shfl,
//     lane(kc) ends owning row kc -> one coalesced 512B store per wave
// Lane layout: kc = lane>>2 (16 k-chunks of 4), qg = lane&3 (q-quad).
// ===========================================================================
#define K1_TPB 256
#define K1_RPW 8                      // rows per wave
#define K1_WPB (K1_TPB / 64)          // 4 waves/block
#define K1_NBLOCKS (ROWS_TOTAL / (K1_RPW * K1_WPB))  // 1024

__device__ __forceinline__ void gload_lds16(const float* g, float* l) {
  __builtin_amdgcn_global_load_lds(
      (const __attribute__((address_space(1))) float*)g,
      (__attribute__((address_space(3))) float*)l, 16, 0, 0);
}

// 16 FMA: x-quad (k=+0..3) against W1 quads A0..A3 (A_m = W1[k+m][4qg..+3])
#define QZ_COMPUTE(BUFI, A0, A1, A2, A3)                                      \
  {                                                                           \
    _Pragma("unroll") for (int r = 0; r < 8; ++r) {                           \
      const float4 xr =                                                       \
          *reinterpret_cast<const float4*>(&xt[wid][BUFI][r][4 * kc]);        \
      acc[r].x = fmaf(xr.x, A0.x, acc[r].x);                                  \
      acc[r].y = fmaf(xr.x, A0.y, acc[r].y);                                  \
      acc[r].z = fmaf(xr.x, A0.z, acc[r].z);                                  \
      acc[r].w = fmaf(xr.x, A0.w, acc[r].w);                                  \
      acc[r].x = fmaf(xr.y, A1.x, acc[r].x);                                  \
      acc[r].y = fmaf(xr.y, A1.y, acc[r].y);                                  \
      acc[r].z = fmaf(xr.y, A1.z, acc[r].z);                                  \
      acc[r].w = fmaf(xr.y, A1.w, acc[r].w);                                  \
      acc[r].x = fmaf(xr.z, A2.x, acc[r].x);                                  \
      acc[r].y = fmaf(xr.z, A2.y, acc[r].y);                                  \
      acc[r].z = fmaf(xr.z, A2.z, acc[r].z);                                  \
      acc[r].w = fmaf(xr.z, A2.w, acc[r].w);                                  \
      acc[r].x = fmaf(xr.w, A3.x, acc[r].x);                                  \
      acc[r].y = fmaf(xr.w, A3.y, acc[r].y);                                  \
      acc[r].z = fmaf(xr.w, A3.z, acc[r].z);                                  \
      acc[r].w = fmaf(xr.w, A3.w, acc[r].w);                                  \
    }                                                                         \
  }

#define QZ_LOADW(SS, D0, D1, D2, D3)                                          \
  {                                                                           \
    const float* pw_ = wsrc + (size_t)(64 * (SS) + 4 * kc) * QDIM;            \
    D0 = *reinterpret_cast<const float4*>(pw_ + 0 * QDIM);                    \
    D1 = *reinterpret_cast<const float4*>(pw_ + 1 * QDIM);                    \
    D2 = *reinterpret_cast<const float4*>(pw_ + 2 * QDIM);                    \
    D3 = *reinterpret_cast<const float4*>(pw_ + 3 * QDIM);                    \
  }

// reduce-scatter stage: hi-lane (PRED) keeps SRC_HI, sends SRC_LO; lo-lane
// keeps SRC_LO, sends SRC_HI. DST may alias SRC_LO (copies taken first).
#define QZ_RS(MASK, PRED, SLO, SHI, DST)                                      \
  {                                                                           \
    float4 snd_, kp_;                                                         \
    snd_.x = (PRED) ? SLO.x : SHI.x;  kp_.x = (PRED) ? SHI.x : SLO.x;         \
    snd_.y = (PRED) ? SLO.y : SHI.y;  kp_.y = (PRED) ? SHI.y : SLO.y;         \
    snd_.z = (PRED) ? SLO.z : SHI.z;  kp_.z = (PRED) ? SHI.z : SLO.z;         \
    snd_.w = (PRED) ? SLO.w : SHI.w;  kp_.w = (PRED) ? SHI.w : SLO.w;         \
    DST.x = kp_.x + __shfl_xor(snd_.x, MASK);                                 \
    DST.y = kp_.y + __shfl_xor(snd_.y, MASK);                                 \
    DST.z = kp_.z + __shfl_xor(snd_.z, MASK);                                 \
    DST.w = kp_.w + __shfl_xor(snd_.w, MASK);                                 \
  }

__global__ __launch_bounds__(K1_TPB)
void qz_kernel(const float* __restrict__ x, const float* __restrict__ W1,
               const float* __restrict__ b1, const float* __restrict__ theta,
               float* __restrict__ z) {
  const int lane = threadIdx.x & 63;
  const int wid = threadIdx.x >> 6;
  const int kc = lane >> 2;  // 0..15
  const int qg = lane & 3;   // 0..3
  const int row0 = (blockIdx.x * K1_WPB + wid) * K1_RPW;

  // per-wave double-buffered x tile: [wave][buf][row][k-in-step]
  __shared__ __align__(16) float xt[K1_WPB][2][K1_RPW][64];  // 16 KB

  // staging lane map (global_load_lds dest = base + lane*16B):
  // instr j fills rows 4j+ (lane>>4), k-offsets 4*(lane&15)
  const float* xs =
      x + (size_t)(row0 + (lane >> 4)) * DDIM + 4 * (lane & 15);
  const float* wsrc = W1 + 4 * qg;

  auto stage = [&](int buf, int s) {
    float* l0 = &xt[wid][buf][0][0];
    gload_lds16(xs + 64 * s, l0);
    gload_lds16(xs + 4 * DDIM + 64 * s, l0 + 4 * 64);
  };

  float4 acc[8];
#pragma unroll
  for (int r = 0; r < 8; ++r) acc[r] = make_float4(0.f, 0.f, 0.f, 0.f);

  float4 ua0, ua1, ua2, ua3, ub0, ub1, ub2, ub3;

  // prologue: tile 0 + W(0)
  stage(0, 0);
  QZ_LOADW(0, ua0, ua1, ua2, ua3);

#pragma unroll 1
  for (int s = 0; s < 14; s += 2) {
    __builtin_amdgcn_sched_barrier(0);
    stage(1, s + 1);
    QZ_LOADW(s + 1, ub0, ub1, ub2, ub3);
    asm volatile("s_waitcnt vmcnt(6)" ::: "memory");  // drain tile s (+W s)
    QZ_COMPUTE(0, ua0, ua1, ua2, ua3)
    __builtin_amdgcn_sched_barrier(0);
    stage(0, s + 2);
    QZ_LOADW(s + 2, ua0, ua1, ua2, ua3);
    asm volatile("s_waitcnt vmcnt(6)" ::: "memory");  // drain tile s+1
    QZ_COMPUTE(1, ub0, ub1, ub2, ub3)
  }
  // s = 14: prefetch 15, compute 14
  __builtin_amdgcn_sched_barrier(0);
  stage(1, 15);
  QZ_LOADW(15, ub0, ub1, ub2, ub3);
  asm volatile("s_waitcnt vmcnt(6)" ::: "memory");
  QZ_COMPUTE(0, ua0, ua1, ua2, ua3)
  // s = 15: final, full drain
  asm volatile("s_waitcnt vmcnt(0)" ::: "memory");
  QZ_COMPUTE(1, ub0, ub1, ub2, ub3)

  // ---- reduce-scatter over kc (lane bits 2..4), then bit-5 butterfly.
  // After stage i, acc[j] holds rows interleaved so that finally acc[0] is
  // row rid = (lane>>2)&7; lanes paired by bit5 duplicate -> lane<32 stores.
  const bool h4 = (lane & 4) != 0;
  const bool h8 = (lane & 8) != 0;
  const bool h16 = (lane & 16) != 0;
  QZ_RS(4, h4, acc[0], acc[1], acc[0])
  QZ_RS(4, h4, acc[2], acc[3], acc[1])
  QZ_RS(4, h4, acc[4], acc[5], acc[2])
  QZ_RS(4, h4, acc[6], acc[7], acc[3])
  QZ_RS(8, h8, acc[0], acc[1], acc[0])
  QZ_RS(8, h8, acc[2], acc[3], acc[1])
  QZ_RS(16, h16, acc[0], acc[1], acc[0])
  acc[0].x += __shfl_xor(acc[0].x, 32);
  acc[0].y += __shfl_xor(acc[0].y, 32);
  acc[0].z += __shfl_xor(acc[0].z, 32);
  acc[0].w += __shfl_xor(acc[0].w, 32);

  if (lane < 32) {
    const int rid = (lane >> 2) & 7;
    const float4 b1v = *reinterpret_cast<const float4*>(b1 + 4 * qg);
    const float4 thv = *reinterpret_cast<const float4*>(theta + 4 * qg);
    float4 zv;
    zv.x = __cosf(fmaxf(acc[0].x + b1v.x, 0.f) + thv.x);
    zv.y = __cosf(fmaxf(acc[0].y + b1v.y, 0.f) + thv.y);
    zv.z = __cosf(fmaxf(acc[0].z + b1v.z, 0.f) + thv.z);
    zv.w = __cosf(fmaxf(acc[0].w + b1v.w, 0.f) + thv.w);
    *reinterpret_cast<float4*>(z + (size_t)(row0 + rid) * QDIM + 4 * qg) = zv;
  }
}

// ===========================================================================
// Pass 2: out[r][d] = b2[d] + sum_q z[r][q] * W2[q][d]
// Thread owns cols 4t..4t+3; W2 slice in 16 NAMED float4 (no arrays, no
// launch_bounds min -- the R3 spill lesson). Per row: 4 uniform-address
// float4 z-loads (L2-hot) + 64 FMA + one coalesced 16B nontemporal store
// via ext_vector f32x4 (HIP_vector_type is rejected by the builtin — R6
// compile failure).
// ===========================================================================
#define K2_TPB 256
#define K2_ROWS 32
#define K2_NBLOCKS (ROWS_TOTAL / K2_ROWS)  // 1024

__global__ __launch_bounds__(K2_TPB)
void out_kernel(const float* __restrict__ z, const float* __restrict__ W2,
                const float* __restrict__ b2, float* __restrict__ out) {
  const int t = threadIdx.x;
  const float* wb = W2 + 4 * t;

  const float4 w00 = *reinterpret_cast<const float4*>(wb + 0 * DDIM);
  const float4 w01 = *reinterpret_cast<const float4*>(wb + 1 * DDIM);
  const float4 w02 = *reinterpret_cast<const float4*>(wb + 2 * DDIM);
  const float4 w03 = *reinterpret_cast<const float4*>(wb + 3 * DDIM);
  const float4 w04 = *reinterpret_cast<const float4*>(wb + 4 * DDIM);
  const float4 w05 = *reinterpret_cast<const float4*>(wb + 5 * DDIM);
  const float4 w06 = *reinterpret_cast<const float4*>(wb + 6 * DDIM);
  const float4 w07 = *reinterpret_cast<const float4*>(wb + 7 * DDIM);
  const float4 w08 = *reinterpret_cast<const float4*>(wb + 8 * DDIM);
  const float4 w09 = *reinterpret_cast<const float4*>(wb + 9 * DDIM);
  const float4 w10 = *reinterpret_cast<const float4*>(wb + 10 * DDIM);
  const float4 w11 = *reinterpret_cast<const float4*>(wb + 11 * DDIM);
  const float4 w12 = *reinterpret_cast<const float4*>(wb + 12 * DDIM);
  const float4 w13 = *reinterpret_cast<const float4*>(wb + 13 * DDIM);
  const float4 w14 = *reinterpret_cast<const float4*>(wb + 14 * DDIM);
  const float4 w15 = *reinterpret_cast<const float4*>(wb + 15 * DDIM);
  const float4 b2v = *reinterpret_cast<const float4*>(b2 + 4 * t);

  auto fmaq = [](float4& a, const float4 zq, const float4 wA, const float4 wB,
                 const float4 wC, const float4 wD) {
    a.x = fmaf(zq.x, wA.x, a.x); a.y = fmaf(zq.x, wA.y, a.y);
    a.z = fmaf(zq.x, wA.z, a.z); a.w = fmaf(zq.x, wA.w, a.w);
    a.x = fmaf(zq.y, wB.x, a.x); a.y = fmaf(zq.y, wB.y, a.y);
    a.z = fmaf(zq.y, wB.z, a.z); a.w = fmaf(zq.y, wB.w, a.w);
    a.x = fmaf(zq.z, wC.x, a.x); a.y = fmaf(zq.z, wC.y, a.y);
    a.z = fmaf(zq.z, wC.z, a.z); a.w = fmaf(zq.z, wC.w, a.w);
    a.x = fmaf(zq.w, wD.x, a.x); a.y = fmaf(zq.w, wD.y, a.y);
    a.z = fmaf(zq.w, wD.z, a.z); a.w = fmaf(zq.w, wD.w, a.w);
  };

  const int r0 = blockIdx.x * K2_ROWS;
  const float* zp = z + (size_t)r0 * QDIM;
  float* op = out + (size_t)r0 * DDIM + 4 * t;

#pragma unroll 4
  for (int i = 0; i < K2_ROWS; ++i) {
    const float4 z0 = *reinterpret_cast<const float4*>(zp + i * QDIM + 0);
    const float4 z1 = *reinterpret_cast<const float4*>(zp + i * QDIM + 4);
    const float4 z2 = *reinterpret_cast<const float4*>(zp + i * QDIM + 8);
    const float4 z3 = *reinterpret_cast<const float4*>(zp + i * QDIM + 12);
    float4 a = b2v;
    fmaq(a, z0, w00, w01, w02, w03);
    fmaq(a, z1, w04, w05, w06, w07);
    fmaq(a, z2, w08, w09, w10, w11);
    fmaq(a, z3, w12, w13, w14, w15);
    f32x4 av;
    av.x = a.x; av.y = a.y; av.z = a.z; av.w = a.w;
    __builtin_nontemporal_store(av,
        reinterpret_cast<f32x4*>(op + (size_t)i * DDIM));
  }
}

// ===========================================================================
// Fallback: previous best fused kernel (used only if ws_size < 2 MB).
// ===========================================================================
#define TPB 512
#define RPB 16
#define R 4
#define NPH (RPB / R)
#define NBLOCKS (ROWS_TOTAL / RPB)

__global__ __launch_bounds__(TPB, 4)
void ffq_kernel(const float* __restrict__ x, const float* __restrict__ W1,
                const float* __restrict__ b1, const float* __restrict__ theta,
                const float* __restrict__ W2, const float* __restrict__ b2,
                float* __restrict__ out) {
  const int t    = threadIdx.x;
  const int lane = t & 63;
  const int wid  = t >> 6;
  const int qg   = t & 3;
  const int c    = t >> 2;
  const int q5   = lane & 15;
  const int r5   = lane >> 4;

  __shared__ __align__(16) float hw[2][16][R][QDIM];
  __shared__ __align__(16) float zs[8][R][QDIM];

  float w1r[8][4];
  {
    const float* p = W1 + (size_t)(8 * c) * QDIM + 4 * qg;
#pragma unroll
    for (int j = 0; j < 8; ++j) {
      float4 v = *reinterpret_cast<const float4*>(p + (size_t)j * QDIM);
      w1r[j][0] = v.x; w1r[j][1] = v.y; w1r[j][2] = v.z; w1r[j][3] = v.w;
    }
  }
  float w2r[QDIM][2];
#pragma unroll
  for (int q = 0; q < QDIM; ++q) {
    float2 v = *reinterpret_cast<const float2*>(W2 + (size_t)q * DDIM + 2 * t);
    w2r[q][0] = v.x; w2r[q][1] = v.y;
  }
  const float2 b2r = *reinterpret_cast<const float2*>(b2 + 2 * t);
  const float b1q = b1[q5];
  const float thq = theta[q5];

  const int row0 = blockIdx.x * RPB;

  float4 xa[R], xb[R];
  {
    const float* p = x + (size_t)row0 * DDIM + 8 * c;
#pragma unroll
    for (int r = 0; r < R; ++r) {
      xa[r] = *reinterpret_cast<const float4*>(p + (size_t)r * DDIM);
      xb[r] = *reinterpret_cast<const float4*>(p + (size_t)r * DDIM + 4);
    }
  }

  auto mm2_store = [&](int rowp) {
#pragma unroll
    for (int r = 0; r < R; ++r) {
      float o0 = b2r.x, o1 = b2r.y;
#pragma unroll
      for (int jb = 0; jb < 4; ++jb) {
        float4 zv = *reinterpret_cast<const float4*>(&zs[wid][r][4 * jb]);
        o0 = fmaf(zv.x, w2r[4 * jb + 0][0], o0);
        o1 = fmaf(zv.x, w2r[4 * jb + 0][1], o1);
        o0 = fmaf(zv.y, w2r[4 * jb + 1][0], o0);
        o1 = fmaf(zv.y, w2r[4 * jb + 1][1], o1);
        o0 = fmaf(zv.z, w2r[4 * jb + 2][0], o0);
        o1 = fmaf(zv.z, w2r[4 * jb + 2][1], o1);
        o0 = fmaf(zv.w, w2r[4 * jb + 3][0], o0);
        o1 = fmaf(zv.w, w2r[4 * jb + 3][1], o1);
      }
      *reinterpret_cast<float2*>(out + (size_t)(rowp + r) * DDIM + 2 * t) =
          make_float2(o0, o1);
    }
  };

  for (int ph = 0; ph < NPH; ++ph) {
    const int buf = ph & 1;

    float hp[R][4];
#pragma unroll
    for (int r = 0; r < R; ++r) {
      const float xv[8] = {xa[r].x, xa[r].y, xa[r].z, xa[r].w,
                           xb[r].x, xb[r].y, xb[r].z, xb[r].w};
      float h0 = 0.f, h1 = 0.f, h2 = 0.f, h3 = 0.f;
#pragma unroll
      for (int j = 0; j < 8; ++j) {
        h0 = fmaf(xv[j], w1r[j][0], h0);
        h1 = fmaf(xv[j], w1r[j][1], h1);
        h2 = fmaf(xv[j], w1r[j][2], h2);
        h3 = fmaf(xv[j], w1r[j][3], h3);
      }
      hp[r][0] = h0; hp[r][1] = h1; hp[r][2] = h2; hp[r][3] = h3;
    }

#pragma unroll
    for (int m = 4; m <= 16; m <<= 1)
#pragma unroll
      for (int r = 0; r < R; ++r)
#pragma unroll
        for (int qq = 0; qq < 4; ++qq)
          hp[r][qq] += __shfl_xor(hp[r][qq], m, 64);

    if ((lane & 28) == 0) {
      const int j = wid * 2 + (lane >> 5);
#pragma unroll
      for (int r = 0; r < R; ++r)
        *reinterpret_cast<float4*>(&hw[buf][j][r][4 * qg]) =
            make_float4(hp[r][0], hp[r][1], hp[r][2], hp[r][3]);
    }
    __syncthreads();

    if (ph + 1 < NPH) {
      const float* p = x + (size_t)(row0 + (ph + 1) * R) * DDIM + 8 * c;
#pragma unroll
      for (int r = 0; r < R; ++r) {
        xa[r] = *reinterpret_cast<const float4*>(p + (size_t)r * DDIM);
        xb[r] = *reinterpret_cast<const float4*>(p + (size_t)r * DDIM + 4);
      }
    }

    if (ph > 0) mm2_store(row0 + (ph - 1) * R);

    float s = 0.f;
#pragma unroll
    for (int j = 0; j < 16; ++j) s += hw[buf][j][r5][q5];
    s = fmaxf(s + b1q, 0.f) + thq;
    zs[wid][r5][q5] = __cosf(s);
  }

  __syncthreads();
  mm2_store(row0 + (NPH - 1) * R);
}

extern "C" void kernel_launch(void* const* d_in, const int* in_sizes, int n_in,
                              void* d_out, int out_size, void* d_ws, size_t ws_size,
                              hipStream_t stream) {
  const float* x     = (const float*)d_in[0];
  const float* W1    = (const float*)d_in[1];
  const float* b1    = (const float*)d_in[2];
  const float* theta = (const float*)d_in[3];
  const float* W2    = (const float*)d_in[4];
  const float* b2    = (const float*)d_in[5];
  float* out = (float*)d_out;

  const size_t z_bytes = (size_t)ROWS_TOTAL * QDIM * sizeof(float);  // 2 MiB
  if (ws_size >= z_bytes && d_ws != nullptr) {
    float* z = (float*)d_ws;
    qz_kernel<<<dim3(K1_NBLOCKS), dim3(K1_TPB), 0, stream>>>(x, W1, b1, theta, z);
    out_kernel<<<dim3(K2_NBLOCKS), dim3(K2_TPB), 0, stream>>>(z, W2, b2, out);
  } else {
    ffq_kernel<<<dim3(NBLOCKS), dim3(TPB), 0, stream>>>(x, W1, b1, theta, W2, b2, out);
  }
}

// Round 8
// 256.986 us; speedup vs baseline: 1.3403x; 1.0210x over previous
//
#include <hip/hip_runtime.h>
#include <math.h>

// Problem constants: B=8, S=4096, D=1024, Q=16  -> 32768 rows
#define ROWS_TOTAL 32768
#define DDIM 1024
#define QDIM 16

typedef float f32x4 __attribute__((ext_vector_type(4)));  // for nt-store

// ===========================================================================
// Pass 1: z[r][q] = cos(relu(x[r]·W1[:,q] + b1[q]) + theta[q])
//
// R7 post-mortem: the half-step schedule's vmcnt(6) forced tile s (staged
// only ~256 cyc earlier) complete -> latency-bound on the x stream (pure
// HBM miss ~900 cyc). R8: K-step 128 (8 steps), LDS dbuf selected by
// runtime address XOR (memory, not regs -> loop stays rolled), and
// LOADW-before-stage issue order so in-order vmcnt retirement gives:
//   steady state: outstanding = {stage(s+1):4, W(cur):4} -> vmcnt(8)
//   tile s+1 staged a FULL iteration (~512 FMA-cyc x TLP) before use.
// Per iter: 8 VMEM + 16 ds_read_b128 feed 256 FMA instrs.
// Lane layout: kc = lane>>2 (16 k-chunks of 4), qg = lane&3 (q-quad).
// Epilogue reduce-scatter unchanged from R7 (verified).
// ===========================================================================
#define K1_TPB 256
#define K1_RPW 8                      // rows per wave
#define K1_WPB (K1_TPB / 64)          // 4 waves/block
#define K1_NBLOCKS (ROWS_TOTAL / (K1_RPW * K1_WPB))  // 1024

__device__ __forceinline__ void gload_lds16(const float* g, float* l) {
  __builtin_amdgcn_global_load_lds(
      (const __attribute__((address_space(1))) float*)g,
      (__attribute__((address_space(3))) float*)l, 16, 0, 0);
}

// 128 FMA: 8 rows x one 16-k... (one 4-k quad per lane) against W quads.
// Tile layout: row r at byte r*512; half h at +h*256; lane quad at +kc*16.
#define QZ_COMPUTE(BASE, H, A0, A1, A2, A3)                                   \
  {                                                                           \
    _Pragma("unroll") for (int r = 0; r < 8; ++r) {                           \
      const float4 xr = *reinterpret_cast<const float4*>(                     \
          (BASE) + r * 128 + (H) * 64 + 4 * kc);                              \
      acc[r].x = fmaf(xr.x, A0.x, acc[r].x);                                  \
      acc[r].y = fmaf(xr.x, A0.y, acc[r].y);                                  \
      acc[r].z = fmaf(xr.x, A0.z, acc[r].z);                                  \
      acc[r].w = fmaf(xr.x, A0.w, acc[r].w);                                  \
      acc[r].x = fmaf(xr.y, A1.x, acc[r].x);                                  \
      acc[r].y = fmaf(xr.y, A1.y, acc[r].y);                                  \
      acc[r].z = fmaf(xr.y, A1.z, acc[r].z);                                  \
      acc[r].w = fmaf(xr.y, A1.w, acc[r].w);                                  \
      acc[r].x = fmaf(xr.z, A2.x, acc[r].x);                                  \
      acc[r].y = fmaf(xr.z, A2.y, acc[r].y);                                  \
      acc[r].z = fmaf(xr.z, A2.z, acc[r].z);                                  \
      acc[r].w = fmaf(xr.z, A2.w, acc[r].w);                                  \
      acc[r].x = fmaf(xr.w, A3.x, acc[r].x);                                  \
      acc[r].y = fmaf(xr.w, A3.y, acc[r].y);                                  \
      acc[r].z = fmaf(xr.w, A3.z, acc[r].z);                                  \
      acc[r].w = fmaf(xr.w, A3.w, acc[r].w);                                  \
    }                                                                         \
  }

// Load W1 rows 64t+4kc..+3, cols 4qg..+3 into 4 named float4 regs.
#define QZ_LOADW(TT, D0, D1, D2, D3)                                          \
  {                                                                           \
    const float* pw_ = wsrc + (size_t)(64 * (TT) + 4 * kc) * QDIM;            \
    D0 = *reinterpret_cast<const float4*>(pw_ + 0 * QDIM);                    \
    D1 = *reinterpret_cast<const float4*>(pw_ + 1 * QDIM);                    \
    D2 = *reinterpret_cast<const float4*>(pw_ + 2 * QDIM);                    \
    D3 = *reinterpret_cast<const float4*>(pw_ + 3 * QDIM);                    \
  }

// reduce-scatter stage (verified R7): hi-lane keeps SRC_HI, sends SRC_LO.
#define QZ_RS(MASK, PRED, SLO, SHI, DST)                                      \
  {                                                                           \
    float4 snd_, kp_;                                                         \
    snd_.x = (PRED) ? SLO.x : SHI.x;  kp_.x = (PRED) ? SHI.x : SLO.x;         \
    snd_.y = (PRED) ? SLO.y : SHI.y;  kp_.y = (PRED) ? SHI.y : SLO.y;         \
    snd_.z = (PRED) ? SLO.z : SHI.z;  kp_.z = (PRED) ? SHI.z : SLO.z;         \
    snd_.w = (PRED) ? SLO.w : SHI.w;  kp_.w = (PRED) ? SHI.w : SLO.w;         \
    DST.x = kp_.x + __shfl_xor(snd_.x, MASK);                                 \
    DST.y = kp_.y + __shfl_xor(snd_.y, MASK);                                 \
    DST.z = kp_.z + __shfl_xor(snd_.z, MASK);                                 \
    DST.w = kp_.w + __shfl_xor(snd_.w, MASK);                                 \
  }

__global__ __launch_bounds__(K1_TPB)
void qz_kernel(const float* __restrict__ x, const float* __restrict__ W1,
               const float* __restrict__ b1, const float* __restrict__ theta,
               float* __restrict__ z) {
  const int lane = threadIdx.x & 63;
  const int wid = threadIdx.x >> 6;
  const int kc = lane >> 2;  // 0..15
  const int qg = lane & 3;   // 0..3
  const int row0 = (blockIdx.x * K1_WPB + wid) * K1_RPW;

  // per-wave double-buffered x tile: [wave][buf][row 8][k 128] = 32 KB/block
  __shared__ __align__(16) float xt[K1_WPB][2][K1_RPW][128];

  // gload_lds dst = base + lane*16B. Instr j covers bytes j*1024+lane*16 of
  // the flat [8][128] tile -> row 2j+(lane>>5), k = 4*(lane&31).
  const float* xs =
      x + (size_t)(row0 + (lane >> 5)) * DDIM + 4 * (lane & 31);
  const float* wsrc = W1 + 4 * qg;

  float* const buf0 = &xt[wid][0][0][0];
  float* const buf1 = &xt[wid][1][0][0];

  auto stage = [&](float* ldst, int s) {
    const float* g = xs + 128 * s;
#pragma unroll
    for (int j = 0; j < 4; ++j)
      gload_lds16(g + (size_t)(2 * j) * DDIM, ldst + j * 256);
  };

  float4 acc[8];
#pragma unroll
  for (int r = 0; r < 8; ++r) acc[r] = make_float4(0.f, 0.f, 0.f, 0.f);

  float4 wa0, wa1, wa2, wa3, wb0, wb1, wb2, wb3;

  // prologue: tile 0 + W half 0
  stage(buf0, 0);
  QZ_LOADW(0, wa0, wa1, wa2, wa3);

  float* cur = buf0;
  float* nxt = buf1;

#pragma unroll 1
  for (int s = 0; s < 7; ++s) {
    // W for this step's odd half (BEFORE stage: decouples retire order)
    QZ_LOADW(2 * s + 1, wb0, wb1, wb2, wb3);
    __builtin_amdgcn_sched_barrier(0);
    stage(nxt, s + 1);
    // steady state: outstanding = W(2s+1):4 + stage(s+1):4 = 8;
    // vmcnt(8) retires tile s + W(2s).
    asm volatile("s_waitcnt vmcnt(8)" ::: "memory");
    QZ_COMPUTE(cur, 0, wa0, wa1, wa2, wa3)
    QZ_LOADW(2 * s + 2, wa0, wa1, wa2, wa3);
    // outstanding: W(2s+1) + stage(s+1) + W(2s+2) = 12; vmcnt(8) retires
    // W(2s+1) WITHOUT forcing stage(s+1) (issued after it... before it —
    // W(2s+1) is oldest, so only it retires).
    asm volatile("s_waitcnt vmcnt(8)" ::: "memory");
    QZ_COMPUTE(cur, 1, wb0, wb1, wb2, wb3)
    float* tmp = cur; cur = nxt; nxt = tmp;
  }
  // tail: step 7 (tile staged in iter 6; no further stage)
  QZ_LOADW(15, wb0, wb1, wb2, wb3);
  // outstanding: stage(7):4 + W(14):4 + W(15):4; need tile7+W14 -> vmcnt(4)
  asm volatile("s_waitcnt vmcnt(4)" ::: "memory");
  QZ_COMPUTE(cur, 0, wa0, wa1, wa2, wa3)
  asm volatile("s_waitcnt vmcnt(0)" ::: "memory");
  QZ_COMPUTE(cur, 1, wb0, wb1, wb2, wb3)

  // ---- reduce-scatter over kc (lane bits 2..4), then bit-5 butterfly.
  const bool h4 = (lane & 4) != 0;
  const bool h8 = (lane & 8) != 0;
  const bool h16 = (lane & 16) != 0;
  QZ_RS(4, h4, acc[0], acc[1], acc[0])
  QZ_RS(4, h4, acc[2], acc[3], acc[1])
  QZ_RS(4, h4, acc[4], acc[5], acc[2])
  QZ_RS(4, h4, acc[6], acc[7], acc[3])
  QZ_RS(8, h8, acc[0], acc[1], acc[0])
  QZ_RS(8, h8, acc[2], acc[3], acc[1])
  QZ_RS(16, h16, acc[0], acc[1], acc[0])
  acc[0].x += __shfl_xor(acc[0].x, 32);
  acc[0].y += __shfl_xor(acc[0].y, 32);
  acc[0].z += __shfl_xor(acc[0].z, 32);
  acc[0].w += __shfl_xor(acc[0].w, 32);

  if (lane < 32) {
    const int rid = (lane >> 2) & 7;
    const float4 b1v = *reinterpret_cast<const float4*>(b1 + 4 * qg);
    const float4 thv = *reinterpret_cast<const float4*>(theta + 4 * qg);
    float4 zv;
    zv.x = __cosf(fmaxf(acc[0].x + b1v.x, 0.f) + thv.x);
    zv.y = __cosf(fmaxf(acc[0].y + b1v.y, 0.f) + thv.y);
    zv.z = __cosf(fmaxf(acc[0].z + b1v.z, 0.f) + thv.z);
    zv.w = __cosf(fmaxf(acc[0].w + b1v.w, 0.f) + thv.w);
    *reinterpret_cast<float4*>(z + (size_t)(row0 + rid) * QDIM + 4 * qg) = zv;
  }
}

// ===========================================================================
// Pass 2 (unchanged from R7, verified): out[r][d] = b2[d] + sum_q z[r][q] *
// W2[q][d]. Thread owns cols 4t..4t+3; W2 slice in 16 NAMED float4. Per
// row: 4 uniform-address float4 z-loads (L2-hot, scalarizable) + 64 FMA +
// one coalesced 16B nontemporal store.
// ===========================================================================
#define K2_TPB 256
#define K2_ROWS 32
#define K2_NBLOCKS (ROWS_TOTAL / K2_ROWS)  // 1024

__global__ __launch_bounds__(K2_TPB)
void out_kernel(const float* __restrict__ z, const float* __restrict__ W2,
                const float* __restrict__ b2, float* __restrict__ out) {
  const int t = threadIdx.x;
  const float* wb = W2 + 4 * t;

  const float4 w00 = *reinterpret_cast<const float4*>(wb + 0 * DDIM);
  const float4 w01 = *reinterpret_cast<const float4*>(wb + 1 * DDIM);
  const float4 w02 = *reinterpret_cast<const float4*>(wb + 2 * DDIM);
  const float4 w03 = *reinterpret_cast<const float4*>(wb + 3 * DDIM);
  const float4 w04 = *reinterpret_cast<const float4*>(wb + 4 * DDIM);
  const float4 w05 = *reinterpret_cast<const float4*>(wb + 5 * DDIM);
  const float4 w06 = *reinterpret_cast<const float4*>(wb + 6 * DDIM);
  const float4 w07 = *reinterpret_cast<const float4*>(wb + 7 * DDIM);
  const float4 w08 = *reinterpret_cast<const float4*>(wb + 8 * DDIM);
  const float4 w09 = *reinterpret_cast<const float4*>(wb + 9 * DDIM);
  const float4 w10 = *reinterpret_cast<const float4*>(wb + 10 * DDIM);
  const float4 w11 = *reinterpret_cast<const float4*>(wb + 11 * DDIM);
  const float4 w12 = *reinterpret_cast<const float4*>(wb + 12 * DDIM);
  const float4 w13 = *reinterpret_cast<const float4*>(wb + 13 * DDIM);
  const float4 w14 = *reinterpret_cast<const float4*>(wb + 14 * DDIM);
  const float4 w15 = *reinterpret_cast<const float4*>(wb + 15 * DDIM);
  const float4 b2v = *reinterpret_cast<const float4*>(b2 + 4 * t);

  auto fmaq = [](float4& a, const float4 zq, const float4 wA, const float4 wB,
                 const float4 wC, const float4 wD) {
    a.x = fmaf(zq.x, wA.x, a.x); a.y = fmaf(zq.x, wA.y, a.y);
    a.z = fmaf(zq.x, wA.z, a.z); a.w = fmaf(zq.x, wA.w, a.w);
    a.x = fmaf(zq.y, wB.x, a.x); a.y = fmaf(zq.y, wB.y, a.y);
    a.z = fmaf(zq.y, wB.z, a.z); a.w = fmaf(zq.y, wB.w, a.w);
    a.x = fmaf(zq.z, wC.x, a.x); a.y = fmaf(zq.z, wC.y, a.y);
    a.z = fmaf(zq.z, wC.z, a.z); a.w = fmaf(zq.z, wC.w, a.w);
    a.x = fmaf(zq.w, wD.x, a.x); a.y = fmaf(zq.w, wD.y, a.y);
    a.z = fmaf(zq.w, wD.z, a.z); a.w = fmaf(zq.w, wD.w, a.w);
  };

  const int r0 = blockIdx.x * K2_ROWS;
  const float* zp = z + (size_t)r0 * QDIM;
  float* op = out + (size_t)r0 * DDIM + 4 * t;

#pragma unroll 4
  for (int i = 0; i < K2_ROWS; ++i) {
    const float4 z0 = *reinterpret_cast<const float4*>(zp + i * QDIM + 0);
    const float4 z1 = *reinterpret_cast<const float4*>(zp + i * QDIM + 4);
    const float4 z2 = *reinterpret_cast<const float4*>(zp + i * QDIM + 8);
    const float4 z3 = *reinterpret_cast<const float4*>(zp + i * QDIM + 12);
    float4 a = b2v;
    fmaq(a, z0, w00, w01, w02, w03);
    fmaq(a, z1, w04, w05, w06, w07);
    fmaq(a, z2, w08, w09, w10, w11);
    fmaq(a, z3, w12, w13, w14, w15);
    f32x4 av;
    av.x = a.x; av.y = a.y; av.z = a.z; av.w = a.w;
    __builtin_nontemporal_store(av,
        reinterpret_cast<f32x4*>(op + (size_t)i * DDIM));
  }
}

// ===========================================================================
// Fallback: previous best fused kernel (used only if ws_size < 2 MB).
// ===========================================================================
#define TPB 512
#define RPB 16
#define R 4
#define NPH (RPB / R)
#define NBLOCKS (ROWS_TOTAL / RPB)

__global__ __launch_bounds__(TPB, 4)
void ffq_kernel(const float* __restrict__ x, const float* __restrict__ W1,
                const float* __restrict__ b1, const float* __restrict__ theta,
                const float* __restrict__ W2, const float* __restrict__ b2,
                float* __restrict__ out) {
  const int t    = threadIdx.x;
  const int lane = t & 63;
  const int wid  = t >> 6;
  const int qg   = t & 3;
  const int c    = t >> 2;
  const int q5   = lane & 15;
  const int r5   = lane >> 4;

  __shared__ __align__(16) float hw[2][16][R][QDIM];
  __shared__ __align__(16) float zs[8][R][QDIM];

  float w1r[8][4];
  {
    const float* p = W1 + (size_t)(8 * c) * QDIM + 4 * qg;
#pragma unroll
    for (int j = 0; j < 8; ++j) {
      float4 v = *reinterpret_cast<const float4*>(p + (size_t)j * QDIM);
      w1r[j][0] = v.x; w1r[j][1] = v.y; w1r[j][2] = v.z; w1r[j][3] = v.w;
    }
  }
  float w2r[QDIM][2];
#pragma unroll
  for (int q = 0; q < QDIM; ++q) {
    float2 v = *reinterpret_cast<const float2*>(W2 + (size_t)q * DDIM + 2 * t);
    w2r[q][0] = v.x; w2r[q][1] = v.y;
  }
  const float2 b2r = *reinterpret_cast<const float2*>(b2 + 2 * t);
  const float b1q = b1[q5];
  const float thq = theta[q5];

  const int row0 = blockIdx.x * RPB;

  float4 xa[R], xb[R];
  {
    const float* p = x + (size_t)row0 * DDIM + 8 * c;
#pragma unroll
    for (int r = 0; r < R; ++r) {
      xa[r] = *reinterpret_cast<const float4*>(p + (size_t)r * DDIM);
      xb[r] = *reinterpret_cast<const float4*>(p + (size_t)r * DDIM + 4);
    }
  }

  auto mm2_store = [&](int rowp) {
#pragma unroll
    for (int r = 0; r < R; ++r) {
      float o0 = b2r.x, o1 = b2r.y;
#pragma unroll
      for (int jb = 0; jb < 4; ++jb) {
        float4 zv = *reinterpret_cast<const float4*>(&zs[wid][r][4 * jb]);
        o0 = fmaf(zv.x, w2r[4 * jb + 0][0], o0);
        o1 = fmaf(zv.x, w2r[4 * jb + 0][1], o1);
        o0 = fmaf(zv.y, w2r[4 * jb + 1][0], o0);
        o1 = fmaf(zv.y, w2r[4 * jb + 1][1], o1);
        o0 = fmaf(zv.z, w2r[4 * jb + 2][0], o0);
        o1 = fmaf(zv.z, w2r[4 * jb + 2][1], o1);
        o0 = fmaf(zv.w, w2r[4 * jb + 3][0], o0);
        o1 = fmaf(zv.w, w2r[4 * jb + 3][1], o1);
      }
      *reinterpret_cast<float2*>(out + (size_t)(rowp + r) * DDIM + 2 * t) =
          make_float2(o0, o1);
    }
  };

  for (int ph = 0; ph < NPH; ++ph) {
    const int buf = ph & 1;

    float hp[R][4];
#pragma unroll
    for (int r = 0; r < R; ++r) {
      const float xv[8] = {xa[r].x, xa[r].y, xa[r].z, xa[r].w,
                           xb[r].x, xb[r].y, xb[r].z, xb[r].w};
      float h0 = 0.f, h1 = 0.f, h2 = 0.f, h3 = 0.f;
#pragma unroll
      for (int j = 0; j < 8; ++j) {
        h0 = fmaf(xv[j], w1r[j][0], h0);
        h1 = fmaf(xv[j], w1r[j][1], h1);
        h2 = fmaf(xv[j], w1r[j][2], h2);
        h3 = fmaf(xv[j], w1r[j][3], h3);
      }
      hp[r][0] = h0; hp[r][1] = h1; hp[r][2] = h2; hp[r][3] = h3;
    }

#pragma unroll
    for (int m = 4; m <= 16; m <<= 1)
#pragma unroll
      for (int r = 0; r < R; ++r)
#pragma unroll
        for (int qq = 0; qq < 4; ++qq)
          hp[r][qq] += __shfl_xor(hp[r][qq], m, 64);

    if ((lane & 28) == 0) {
      const int j = wid * 2 + (lane >> 5);
#pragma unroll
      for (int r = 0; r < R; ++r)
        *reinterpret_cast<float4*>(&hw[buf][j][r][4 * qg]) =
            make_float4(hp[r][0], hp[r][1], hp[r][2], hp[r][3]);
    }
    __syncthreads();

    if (ph + 1 < NPH) {
      const float* p = x + (size_t)(row0 + (ph + 1) * R) * DDIM + 8 * c;
#pragma unroll
      for (int r = 0; r < R; ++r) {
        xa[r] = *reinterpret_cast<const float4*>(p + (size_t)r * DDIM);
        xb[r] = *reinterpret_cast<const float4*>(p + (size_t)r * DDIM + 4);
      }
    }

    if (ph > 0) mm2_store(row0 + (ph - 1) * R);

    float s = 0.f;
#pragma unroll
    for (int j = 0; j < 16; ++j) s += hw[buf][j][r5][q5];
    s = fmaxf(s + b1q, 0.f) + thq;
    zs[wid][r5][q5] = __cosf(s);
  }

  __syncthreads();
  mm2_store(row0 + (NPH - 1) * R);
}

extern "C" void kernel_launch(void* const* d_in, const int* in_sizes, int n_in,
                              void* d_out, int out_size, void* d_ws, size_t ws_size,
                              hipStream_t stream) {
  const float* x     = (const float*)d_in[0];
  const float* W1    = (const float*)d_in[1];
  const float* b1    = (const float*)d_in[2];
  const float* theta = (const float*)d_in[3];
  const float* W2    = (const float*)d_in[4];
  const float* b2    = (const float*)d_in[5];
  float* out = (float*)d_out;

  const size_t z_bytes = (size_t)ROWS_TOTAL * QDIM * sizeof(float);  // 2 MiB
  if (ws_size >= z_bytes && d_ws != nullptr) {
    float* z = (float*)d_ws;
    qz_kernel<<<dim3(K1_NBLOCKS), dim3(K1_TPB), 0, stream>>>(x, W1, b1, theta, z);
    out_kernel<<<dim3(K2_NBLOCKS), dim3(K2_TPB), 0, stream>>>(z, W2, b2, out);
  } else {
    ffq_kernel<<<dim3(NBLOCKS), dim3(TPB), 0, stream>>>(x, W1, b1, theta, W2, b2, out);
  }
}